// Round 5
// baseline (496.692 us; speedup 1.0000x reference)
//
#include <hip/hip_runtime.h>
#include <hip/hip_bf16.h>
#include <cstdint>
#include <cstddef>

#define NN 50000
#define NE 400000
typedef long long i64;
typedef unsigned short u16;
typedef __attribute__((ext_vector_type(8))) short bf16x8;
typedef __attribute__((ext_vector_type(8))) unsigned short u16x8;
typedef __attribute__((ext_vector_type(4))) float f32x4;

__device__ inline u16 f2bf(float f) {  // RNE
    unsigned u = __float_as_uint(f);
    u += 0x7fffu + ((u >> 16) & 1u);
    return (u16)(u >> 16);
}
__device__ inline float bf2f(u16 b) { return __uint_as_float(((unsigned)b) << 16); }

// ---------------- setup kernels ----------------
__global__ void k_init(int* __restrict__ deg, int* __restrict__ flag) {
    int i = blockIdx.x * blockDim.x + threadIdx.x;
    if (i < NN) deg[i] = 0;
    if (i == 0) *flag = 0;
}

__global__ void k_detect(const void* __restrict__ ei, int* __restrict__ flag) {
    int i = blockIdx.x * blockDim.x + threadIdx.x;
    if (i < NE) {
        i64 v = ((const i64*)ei)[i];
        if (v < 0 || v >= NN) atomicOr(flag, 1);
    }
}

__device__ inline int edge_at(const void* ei, int f32idx, int half, int i) {
    if (f32idx) return ((const int*)ei)[half * NE + i];
    return (int)((const i64*)ei)[half * NE + i];
}

__global__ void k_hist(const void* __restrict__ ei, const int* __restrict__ flag,
                       int* __restrict__ deg) {
    int i = blockIdx.x * blockDim.x + threadIdx.x;
    if (i < NE) {
        int d = edge_at(ei, *flag, 1, i);
        if ((unsigned)d < NN) atomicAdd(&deg[d], 1);
    }
}

__global__ void k_node_setup(const int* __restrict__ deg, float* __restrict__ inv_sqrt,
                             float* __restrict__ inv_deg) {
    int i = blockIdx.x * blockDim.x + threadIdx.x;
    if (i < NN) {
        float d = (float)deg[i] + 1.0f;
        inv_sqrt[i] = rsqrtf(d);
        inv_deg[i]  = 1.0f / d;
    }
}

// ---------------- 3-phase parallel scan ----------------
#define SB 256
#define NBLK ((NN + SB - 1) / SB)  // 196

__global__ __launch_bounds__(SB) void k_scan1(const int* __restrict__ deg,
                                              int* __restrict__ excl,
                                              int* __restrict__ bsum) {
    __shared__ int s[SB];
    int t = threadIdx.x;
    int i = blockIdx.x * SB + t;
    int v = (i < NN) ? deg[i] : 0;
    s[t] = v;
    __syncthreads();
    for (int off = 1; off < SB; off <<= 1) {
        int x = (t >= off) ? s[t - off] : 0;
        __syncthreads();
        s[t] += x;
        __syncthreads();
    }
    if (i < NN) excl[i] = s[t] - v;
    if (t == SB - 1) bsum[blockIdx.x] = s[t];
}

__global__ __launch_bounds__(SB) void k_scan2(int* __restrict__ bsum) {
    __shared__ int s[SB];
    int t = threadIdx.x;
    int v = (t < NBLK) ? bsum[t] : 0;
    s[t] = v;
    __syncthreads();
    for (int off = 1; off < SB; off <<= 1) {
        int x = (t >= off) ? s[t - off] : 0;
        __syncthreads();
        s[t] += x;
        __syncthreads();
    }
    if (t < NBLK) bsum[t] = s[t] - v;
    if (t == NBLK - 1) bsum[NBLK] = s[t];
}

__global__ __launch_bounds__(SB) void k_scan3(int* __restrict__ row_off,
                                              int* __restrict__ cursor,
                                              const int* __restrict__ bsum) {
    int i = blockIdx.x * SB + threadIdx.x;
    if (i < NN) {
        int r = row_off[i] + bsum[blockIdx.x];
        row_off[i] = r;
        cursor[i]  = r;
    }
    if (i == 0) row_off[NN] = bsum[NBLK];
}

__global__ void k_scatter(const void* __restrict__ ei, const int* __restrict__ flag,
                          const float* __restrict__ inv_sqrt,
                          int* __restrict__ cursor, int* __restrict__ ssrc,
                          float* __restrict__ snorm) {
    int i = blockIdx.x * blockDim.x + threadIdx.x;
    if (i < NE) {
        int f = *flag;
        int s = edge_at(ei, f, 0, i);
        int d = edge_at(ei, f, 1, i);
        if ((unsigned)s < NN && (unsigned)d < NN) {
            int pos = atomicAdd(&cursor[d], 1);
            if ((unsigned)pos < NE) {
                ssrc[pos]  = s;
                snorm[pos] = inv_sqrt[s] * inv_sqrt[d];
            }
        }
    }
}

// ---------------- weight convert + transpose: Wt[n][k] = bf16(W[k][n]) ----------------
__global__ void k_wt(const float* __restrict__ W, u16* __restrict__ Wt, int K, int N) {
    int i = blockIdx.x * 256 + threadIdx.x;
    if (i < K * N) {
        int k = i / N, n = i - k * N;
        Wt[(size_t)n * K + k] = f2bf(W[i]);
    }
}

// ---------------- CSR aggregation ----------------
template <int W, int TIN, int TOUT, bool BIAS, bool RELU>
__global__ __launch_bounds__(64) void k_agg(const void* __restrict__ Xv, void* __restrict__ Yv,
                      const int* __restrict__ row_off, const int* __restrict__ ssrc,
                      const float* __restrict__ snorm, const float* __restrict__ inv_deg,
                      const float* __restrict__ bias) {
    constexpr int E = W / 64;
    int node = blockIdx.x;
    int lane = threadIdx.x;
    int col = lane * E;
    int beg = row_off[node], end = row_off[node + 1];
    float acc[E];
#pragma unroll
    for (int v = 0; v < E; v++) acc[v] = 0.f;

    auto accum = [&](int srow, float w) {
        if constexpr (TIN == 0) {
            const float* r = (const float*)Xv + (size_t)srow * W + col;
            if constexpr (E == 2) {
                float2 t = *(const float2*)r;
                acc[0] = fmaf(t.x, w, acc[0]);
                acc[1] = fmaf(t.y, w, acc[1]);
            } else {
                float4 t0 = *(const float4*)r;
                float4 t1 = *(const float4*)(r + 4);
                acc[0] = fmaf(t0.x, w, acc[0]); acc[1] = fmaf(t0.y, w, acc[1]);
                acc[2] = fmaf(t0.z, w, acc[2]); acc[3] = fmaf(t0.w, w, acc[3]);
                acc[4] = fmaf(t1.x, w, acc[4]); acc[5] = fmaf(t1.y, w, acc[5]);
                acc[6] = fmaf(t1.z, w, acc[6]); acc[7] = fmaf(t1.w, w, acc[7]);
            }
        } else {
            const u16* r = (const u16*)Xv + (size_t)srow * W + col;
            if constexpr (E == 2) {
                unsigned t = *(const unsigned*)r;
                acc[0] = fmaf(bf2f((u16)(t & 0xffff)), w, acc[0]);
                acc[1] = fmaf(bf2f((u16)(t >> 16)), w, acc[1]);
            } else {
                u16x8 t = *(const u16x8*)r;
#pragma unroll
                for (int j = 0; j < 8; j++) acc[j] = fmaf(bf2f(t[j]), w, acc[j]);
            }
        }
    };

    for (int e = beg; e < end; e++) {
        int s = ssrc[e];
        if ((unsigned)s >= NN) continue;
        accum(s, snorm[e]);
    }
    accum(node, inv_deg[node]);

#pragma unroll
    for (int v = 0; v < E; v++) {
        float val = acc[v];
        if (BIAS) val += bias[col + v];
        if (RELU) val = fmaxf(val, 0.f);
        if constexpr (TOUT == 0) ((float*)Yv)[(size_t)node * W + col + v] = val;
        else ((u16*)Yv)[(size_t)node * W + col + v] = f2bf(val);
    }
}

#define LDS_AS(p) ((__attribute__((address_space(3))) void*)(p))
#define GLB_AS(p) ((const __attribute__((address_space(1))) void*)(p))

// ---------------- deep-pipelined 256x256 bf16 MFMA GEMM ----------------
// C[M][N] = A[M][K] * Bt[N][K]^T. 512 threads = 8 waves (2M x 4N),
// per-wave output 128x64. LDS: 4-slot ring (BK=32 each) -> staging runs
// 3 K-steps ahead, 1 barrier + vmcnt(8) per K-step (T3+T4). T2 chunk-XOR
// swizzle applied on global SOURCE (LDS dest linear, rule #21) and on the
// ds_read address. T5 setprio around MFMA clusters. T1 XCD swizzle.
template <bool BIAS, bool RELU>
__global__ __launch_bounds__(512, 2) void gemm8p(
    const u16* __restrict__ A,   // [M][K] bf16
    const u16* __restrict__ Bt,  // [N][K] bf16
    const float* __restrict__ bias,
    u16* __restrict__ C,         // [M][N] bf16
    int M, int N, int K) {
    __shared__ __align__(16) u16 As[4 * 8192];  // 4 slots x 256rows x 32k = 64KB
    __shared__ __align__(16) u16 Bs[4 * 8192];  // 64KB
    const int tid  = threadIdx.x;
    const int lane = tid & 63;
    const int wave = tid >> 6;
    const int wm = wave >> 2;        // 0..1
    const int wn = wave & 3;         // 0..3

    // bijective XCD swizzle (m204)
    const int nwg = gridDim.x;
    int swz;
    { int q = nwg >> 3, r = nwg & 7, xc = blockIdx.x & 7, o = blockIdx.x >> 3;
      swz = (xc < r ? xc * (q + 1) : r * (q + 1) + (xc - r) * q) + o; }
    const int nbn = N >> 8;
    const int bm = (swz / nbn) << 8;
    const int bn = (swz % nbn) << 8;

    const int nt = K >> 5;  // K-steps of 32

    f32x4 acc[8][4];
#pragma unroll
    for (int m = 0; m < 8; m++)
#pragma unroll
        for (int n = 0; n < 4; n++) acc[m][n] = (f32x4)0.f;

    // ---- staging descriptors: 2 x 16B per matrix per K-step per thread ----
    // LDS slot layout (linear dest): o = row*64B + chunk*16B, row 0..255.
    // Source pre-swizzle: chunk' = chunk ^ (row&3)  (T2, both-sides).
    const int o0 = tid * 16;
    const int o1 = o0 + 8192;
    const char* Ab = (const char*)A;
    const char* Bb = (const char*)Bt;
    const int row0 = o0 >> 6, row1 = o1 >> 6;
    const int in0 = (o0 & 63) ^ ((row0 & 3) << 4);
    const int in1 = (o1 & 63) ^ ((row1 & 3) << 4);
    int ra0 = bm + row0; if (ra0 > M - 1) ra0 = M - 1;
    int ra1 = bm + row1; if (ra1 > M - 1) ra1 = M - 1;
    int rb0 = bn + row0; if (rb0 > N - 1) rb0 = N - 1;
    int rb1 = bn + row1; if (rb1 > N - 1) rb1 = N - 1;
    const size_t sK = (size_t)K * 2;
    const size_t gA0 = (size_t)ra0 * sK + in0;
    const size_t gA1 = (size_t)ra1 * sK + in1;
    const size_t gB0 = (size_t)rb0 * sK + in0;
    const size_t gB1 = (size_t)rb1 * sK + in1;

    auto stageA = [&](int t) {
        const int slot = (t & 3) * 16384;
        const size_t kb = (size_t)t * 64;
        __builtin_amdgcn_global_load_lds(GLB_AS(Ab + gA0 + kb), LDS_AS((char*)As + slot + o0), 16, 0, 0);
        __builtin_amdgcn_global_load_lds(GLB_AS(Ab + gA1 + kb), LDS_AS((char*)As + slot + o1), 16, 0, 0);
    };
    auto stageB = [&](int t) {
        const int slot = (t & 3) * 16384;
        const size_t kb = (size_t)t * 64;
        __builtin_amdgcn_global_load_lds(GLB_AS(Bb + gB0 + kb), LDS_AS((char*)Bs + slot + o0), 16, 0, 0);
        __builtin_amdgcn_global_load_lds(GLB_AS(Bb + gB1 + kb), LDS_AS((char*)Bs + slot + o1), 16, 0, 0);
    };

    // fragment read offsets (byte, within slot): row*64 + (chunk^(row&3))*16
    const int fr = lane & 15;
    const int laneA = fr * 64 + ((((lane >> 4) ^ (fr & 3)) << 4));

    // prologue: stage K-steps 0..2 (FIFO: A0,B0,A1,B1,A2,B2 = 12 loads)
    const int ps = nt < 3 ? nt : 3;
    for (int s = 0; s < ps; ++s) { stageA(s); stageB(s); }

    for (int t = 0; t < nt; ++t) {
        const int slot = (t & 3) * 16384;
        const int rem = nt - 1 - t;
        // slot t complete when <= (outstanding newer loads) remain:
        // steps t+1,t+2 in flight = 8 loads (4 if rem==1, 0 if rem==0)
        if (rem >= 2)      asm volatile("s_waitcnt vmcnt(8)\ns_barrier" ::: "memory");
        else if (rem == 1) asm volatile("s_waitcnt vmcnt(4)\ns_barrier" ::: "memory");
        else               asm volatile("s_waitcnt vmcnt(0)\ns_barrier" ::: "memory");
        // barrier passed => all waves done reading slot (t-1)&3 == (t+3)&3
        if (t + 3 < nt) stageA(t + 3);

        const char* Asl = (const char*)As + slot;
        const char* Bsl = (const char*)Bs + slot;
        bf16x8 bfrg[4];
#pragma unroll
        for (int n = 0; n < 4; n++)
            bfrg[n] = *(const bf16x8*)(Bsl + (wn * 64 + n * 16) * 64 + laneA);
        bf16x8 afrg[4];
#pragma unroll
        for (int m = 0; m < 4; m++)
            afrg[m] = *(const bf16x8*)(Asl + (wm * 128 + m * 16) * 64 + laneA);
        __builtin_amdgcn_s_setprio(1);
#pragma unroll
        for (int m = 0; m < 4; m++)
#pragma unroll
            for (int n = 0; n < 4; n++)
                acc[m][n] = __builtin_amdgcn_mfma_f32_16x16x32_bf16(afrg[m], bfrg[n], acc[m][n], 0, 0, 0);
        __builtin_amdgcn_s_setprio(0);

        if (t + 3 < nt) stageB(t + 3);
#pragma unroll
        for (int m = 0; m < 4; m++)
            afrg[m] = *(const bf16x8*)(Asl + (wm * 128 + (m + 4) * 16) * 64 + laneA);
        __builtin_amdgcn_s_setprio(1);
#pragma unroll
        for (int m = 0; m < 4; m++)
#pragma unroll
            for (int n = 0; n < 4; n++)
                acc[m + 4][n] = __builtin_amdgcn_mfma_f32_16x16x32_bf16(afrg[m], bfrg[n], acc[m + 4][n], 0, 0, 0);
        __builtin_amdgcn_s_setprio(0);
    }

    // epilogue: C/D layout col=lane&15, row=4*(lane>>4)+reg
    const int cr = (lane >> 4) << 2;
    const int cc = lane & 15;
#pragma unroll
    for (int n = 0; n < 4; n++) {
        int col = bn + wn * 64 + n * 16 + cc;
        float bv = BIAS ? bias[col] : 0.f;
#pragma unroll
        for (int m = 0; m < 8; m++) {
#pragma unroll
            for (int j = 0; j < 4; j++) {
                int row = bm + wm * 128 + m * 16 + cr + j;
                if (row < M) {
                    float v = acc[m][n][j] + bv;
                    if (RELU) v = fmaxf(v, 0.f);
                    C[(size_t)row * N + col] = f2bf(v);
                }
            }
        }
    }
}

// ---------------- m97-style 128x128 MFMA GEMM (kept for L3, N=128) ----------------
#define GBM 128
#define GBN 128
#define GBK 32

template <bool BIAS, bool RELU>
__global__ __launch_bounds__(256) void mfma_gemm(
    const u16* __restrict__ A, const u16* __restrict__ Bt,
    const float* __restrict__ bias, u16* __restrict__ C,
    int M, int N, int K) {
    __shared__ __align__(16) u16 As[GBM * GBK];
    __shared__ __align__(16) u16 Bs[GBN * GBK];
    const int tid = threadIdx.x;
    const int lane = tid & 63;
    const int wave = tid >> 6;
    const int wr = wave >> 1, wc = wave & 1;
    const int bm = blockIdx.y * GBM;
    const int bn = blockIdx.x * GBN;

    f32x4 acc[4][4];
#pragma unroll
    for (int m = 0; m < 4; m++)
#pragma unroll
        for (int n = 0; n < 4; n++) acc[m][n] = (f32x4)0.f;

    const int o = tid * 16;
    const int row0 = o >> 6;
    const int colb = o & 63;
    const int row1 = row0 + 64;

    int ar0 = bm + row0; if (ar0 >= M) ar0 = M - 1;
    int ar1 = bm + row1; if (ar1 >= M) ar1 = M - 1;
    const int br0 = bn + row0;
    const int br1 = bn + row1;
    const size_t sK = (size_t)K * 2;

    const char* Ab = (const char*)A;
    const char* Bb = (const char*)Bt;

    const int kc = (lane >> 4) << 3;
    const int fr = lane & 15;
    const u16* ApA = &As[(wr * 64 + fr) * GBK + kc];
    const u16* BpB = &Bs[(wc * 64 + fr) * GBK + kc];

    for (int k0 = 0; k0 < K; k0 += GBK) {
        const size_t kb = (size_t)k0 * 2 + colb;
        __builtin_amdgcn_global_load_lds(GLB_AS(Ab + (size_t)ar0 * sK + kb), LDS_AS((char*)As + o), 16, 0, 0);
        __builtin_amdgcn_global_load_lds(GLB_AS(Ab + (size_t)ar1 * sK + kb), LDS_AS((char*)As + o + 4096), 16, 0, 0);
        __builtin_amdgcn_global_load_lds(GLB_AS(Bb + (size_t)br0 * sK + kb), LDS_AS((char*)Bs + o), 16, 0, 0);
        __builtin_amdgcn_global_load_lds(GLB_AS(Bb + (size_t)br1 * sK + kb), LDS_AS((char*)Bs + o + 4096), 16, 0, 0);
        __syncthreads();

        bf16x8 af[4], bfr[4];
#pragma unroll
        for (int m = 0; m < 4; m++) af[m] = *(const bf16x8*)(ApA + m * 16 * GBK);
#pragma unroll
        for (int n = 0; n < 4; n++) bfr[n] = *(const bf16x8*)(BpB + n * 16 * GBK);
#pragma unroll
        for (int m = 0; m < 4; m++)
#pragma unroll
            for (int n = 0; n < 4; n++)
                acc[m][n] = __builtin_amdgcn_mfma_f32_16x16x32_bf16(af[m], bfr[n], acc[m][n], 0, 0, 0);
        __syncthreads();
    }

    const int cr = (lane >> 4) << 2;
    const int cc = lane & 15;
#pragma unroll
    for (int n = 0; n < 4; n++) {
        int col = bn + wc * 64 + n * 16 + cc;
        float bv = BIAS ? bias[col] : 0.f;
#pragma unroll
        for (int m = 0; m < 4; m++) {
#pragma unroll
            for (int j = 0; j < 4; j++) {
                int row = bm + wr * 64 + m * 16 + cr + j;
                if (row < M) {
                    float v = acc[m][n][j] + bv;
                    if (RELU) v = fmaxf(v, 0.f);
                    C[(size_t)row * N + col] = f2bf(v);
                }
            }
        }
    }
}

// ---------------- f32 tiled GEMM (small FC layer) ----------------
#define TBM 64
#define TBN 64
#define TBK 16
#define LPAD 4

template <bool BIAS, bool RELU>
__global__ __launch_bounds__(256) void gemm_kernel(
    const float* __restrict__ A, const float* __restrict__ B,
    const float* __restrict__ bias, float* __restrict__ C,
    int M, int N, int K) {
    __shared__ float Asl[TBK][TBM + LPAD];
    __shared__ float Bsl[TBK][TBN + LPAD];
    const int bm = blockIdx.y * TBM;
    const int bn = blockIdx.x * TBN;
    const int tid = threadIdx.x;
    const int tx = tid & 15;
    const int ty = tid >> 4;
    const int la_m = tid >> 2;
    const int la_k = (tid & 3) << 2;
    const int lb_k = tid >> 4;
    const int lb_n = (tid & 15) << 2;

    float acc[4][4];
#pragma unroll
    for (int i = 0; i < 4; i++)
#pragma unroll
        for (int j = 0; j < 4; j++) acc[i][j] = 0.f;

    const int am = bm + la_m;
    const bool a_ok = am < M;
    const int bng = bn + lb_n;

    for (int k0 = 0; k0 < K; k0 += TBK) {
        float4 av = make_float4(0.f, 0.f, 0.f, 0.f);
        if (a_ok) av = *(const float4*)(A + (size_t)am * K + k0 + la_k);
        float4 bv = make_float4(0.f, 0.f, 0.f, 0.f);
        {
            const float* Bp = B + (size_t)(k0 + lb_k) * N + bng;
            if (bng + 3 < N) {
                bv = *(const float4*)Bp;
            } else {
                if (bng + 0 < N) bv.x = Bp[0];
                if (bng + 1 < N) bv.y = Bp[1];
                if (bng + 2 < N) bv.z = Bp[2];
            }
        }
        Asl[la_k + 0][la_m] = av.x;
        Asl[la_k + 1][la_m] = av.y;
        Asl[la_k + 2][la_m] = av.z;
        Asl[la_k + 3][la_m] = av.w;
        *(float4*)&Bsl[lb_k][lb_n] = bv;
        __syncthreads();
#pragma unroll
        for (int k = 0; k < TBK; k++) {
            float4 a = *(const float4*)&Asl[k][ty << 2];
            float4 b = *(const float4*)&Bsl[k][tx << 2];
            float aa[4] = {a.x, a.y, a.z, a.w};
            float bb[4] = {b.x, b.y, b.z, b.w};
#pragma unroll
            for (int i = 0; i < 4; i++)
#pragma unroll
                for (int j = 0; j < 4; j++)
                    acc[i][j] = fmaf(aa[i], bb[j], acc[i][j]);
        }
        __syncthreads();
    }
#pragma unroll
    for (int i = 0; i < 4; i++) {
        int m = bm + (ty << 2) + i;
        if (m < M) {
#pragma unroll
            for (int j = 0; j < 4; j++) {
                int n = bn + (tx << 2) + j;
                if (n < N) {
                    float v = acc[i][j];
                    if (BIAS) v += bias[n];
                    if (RELU) v = fmaxf(v, 0.f);
                    C[(size_t)m * N + n] = v;
                }
            }
        }
    }
}

// ---------------- launch ----------------
extern "C" void kernel_launch(void* const* d_in, const int* in_sizes, int n_in,
                              void* d_out, int out_size, void* d_ws, size_t ws_size,
                              hipStream_t stream) {
    const float* x   = (const float*)d_in[0];
    const void*  ei  = d_in[1];
    const float* W1  = (const float*)d_in[2];
    const float* b1  = (const float*)d_in[3];
    const float* W2  = (const float*)d_in[4];
    const float* b2  = (const float*)d_in[5];
    const float* W3  = (const float*)d_in[6];
    const float* b3  = (const float*)d_in[7];
    const float* Wfc = (const float*)d_in[8];
    const float* bfc = (const float*)d_in[9];
    float* out = (float*)d_out;

    char* ws = (char*)d_ws;
    size_t off = 0;
    auto take = [&](size_t bytes) -> void* {
        off = (off + 255) & ~(size_t)255;
        void* p = ws + off;
        off += bytes;
        return p;
    };
    int*   deg     = (int*)take((size_t)NN * 4);
    int*   row_off = (int*)take((size_t)(NN + 1) * 4);
    int*   cursor  = (int*)take((size_t)NN * 4);
    float* isq     = (float*)take((size_t)NN * 4);
    float* idg     = (float*)take((size_t)NN * 4);
    int*   ssrc    = (int*)take((size_t)NE * 4);
    float* snorm   = (float*)take((size_t)NE * 4);
    int*   flag    = (int*)take(256);
    int*   bsum    = (int*)take((size_t)(NBLK + 1) * 4);
    u16*   Wt1     = (u16*)take((size_t)1024 * 128 * 2);
    u16*   Wt2     = (u16*)take((size_t)512 * 1024 * 2);
    u16*   Wt3     = (u16*)take((size_t)128 * 512 * 2);
    u16*   rA      = (u16*)take((size_t)NN * 128 * 2);   // a0, later g3
    u16*   rH      = (u16*)take((size_t)NN * 1024 * 2);  // h1, later h2
    u16*   rT      = (u16*)take((size_t)NN * 512 * 2);   // t2
    float* h3      = (float*)take((size_t)NN * 128 * 4);

    // graph setup
    k_init<<<(NN + 255) / 256, 256, 0, stream>>>(deg, flag);
    k_detect<<<(NE + 255) / 256, 256, 0, stream>>>(ei, flag);
    k_hist<<<(NE + 255) / 256, 256, 0, stream>>>(ei, flag, deg);
    k_node_setup<<<(NN + 255) / 256, 256, 0, stream>>>(deg, isq, idg);
    k_scan1<<<NBLK, SB, 0, stream>>>(deg, row_off, bsum);
    k_scan2<<<1, SB, 0, stream>>>(bsum);
    k_scan3<<<NBLK, SB, 0, stream>>>(row_off, cursor, bsum);
    k_scatter<<<(NE + 255) / 256, 256, 0, stream>>>(ei, flag, isq, cursor, ssrc, snorm);

    // weights -> bf16 transposed
    k_wt<<<(128 * 1024 + 255) / 256, 256, 0, stream>>>(W1, Wt1, 128, 1024);
    k_wt<<<(1024 * 512 + 255) / 256, 256, 0, stream>>>(W2, Wt2, 1024, 512);
    k_wt<<<(512 * 128 + 255) / 256, 256, 0, stream>>>(W3, Wt3, 512, 128);

    const int MB256 = (NN + 255) / 256;  // 196

    // L1: aggregate x (f32 -> bf16), pipelined GEMM(+b1,relu) -> h1
    u16* a0 = rA;
    k_agg<128, 0, 1, false, false><<<NN, 64, 0, stream>>>(x, a0, row_off, ssrc, snorm, idg, nullptr);
    u16* h1 = rH;
    gemm8p<true, true><<<MB256 * (1024 / 256), 512, 0, stream>>>(a0, Wt1, b1, h1, NN, 1024, 128);

    // L2: pipelined GEMM -> t2, aggregate(+b2,relu) -> h2
    u16* t2 = rT;
    gemm8p<false, false><<<MB256 * (512 / 256), 512, 0, stream>>>(h1, Wt2, nullptr, t2, NN, 512, 1024);
    u16* h2 = rH;  // h1 dead
    k_agg<512, 1, 1, true, true><<<NN, 64, 0, stream>>>(t2, h2, row_off, ssrc, snorm, idg, b2);

    // L3: GEMM -> g3, aggregate(+b3,relu) -> h3 (f32)
    u16* g3 = rA;  // a0 dead
    mfma_gemm<false, false><<<dim3(1, (NN + GBM - 1) / GBM), 256, 0, stream>>>(h2, Wt3, nullptr, g3, NN, 128, 512);
    k_agg<128, 1, 0, true, true><<<NN, 64, 0, stream>>>(g3, h3, row_off, ssrc, snorm, idg, b3);

    // FC (f32)
    gemm_kernel<true, false><<<dim3(1, (NN + TBM - 1) / TBM), 256, 0, stream>>>(h3, Wfc, bfc, out, NN, 40, 128);

    (void)in_sizes; (void)n_in; (void)out_size; (void)ws_size;
}

// Round 6
// 457.557 us; speedup vs baseline: 1.0855x; 1.0855x over previous
//
#include <hip/hip_runtime.h>
#include <hip/hip_bf16.h>
#include <cstdint>
#include <cstddef>

#define NN 50000
#define NE 400000
typedef long long i64;
typedef unsigned short u16;
typedef __attribute__((ext_vector_type(8))) short bf16x8;
typedef __attribute__((ext_vector_type(8))) unsigned short u16x8;
typedef __attribute__((ext_vector_type(4))) float f32x4;

__device__ inline u16 f2bf(float f) {  // RNE
    unsigned u = __float_as_uint(f);
    u += 0x7fffu + ((u >> 16) & 1u);
    return (u16)(u >> 16);
}
__device__ inline float bf2f(u16 b) { return __uint_as_float(((unsigned)b) << 16); }

// ---------------- setup kernels ----------------
__global__ void k_init(int* __restrict__ deg, int* __restrict__ flag) {
    int i = blockIdx.x * blockDim.x + threadIdx.x;
    if (i < NN) deg[i] = 0;
    if (i == 0) *flag = 0;
}

__global__ void k_detect(const void* __restrict__ ei, int* __restrict__ flag) {
    int i = blockIdx.x * blockDim.x + threadIdx.x;
    if (i < NE) {
        i64 v = ((const i64*)ei)[i];
        if (v < 0 || v >= NN) atomicOr(flag, 1);
    }
}

__device__ inline int edge_at(const void* ei, int f32idx, int half, int i) {
    if (f32idx) return ((const int*)ei)[half * NE + i];
    return (int)((const i64*)ei)[half * NE + i];
}

__global__ void k_hist(const void* __restrict__ ei, const int* __restrict__ flag,
                       int* __restrict__ deg) {
    int i = blockIdx.x * blockDim.x + threadIdx.x;
    if (i < NE) {
        int d = edge_at(ei, *flag, 1, i);
        if ((unsigned)d < NN) atomicAdd(&deg[d], 1);
    }
}

__global__ void k_node_setup(const int* __restrict__ deg, float* __restrict__ inv_sqrt,
                             float* __restrict__ inv_deg) {
    int i = blockIdx.x * blockDim.x + threadIdx.x;
    if (i < NN) {
        float d = (float)deg[i] + 1.0f;
        inv_sqrt[i] = rsqrtf(d);
        inv_deg[i]  = 1.0f / d;
    }
}

// ---------------- 3-phase parallel scan ----------------
#define SB 256
#define NBLK ((NN + SB - 1) / SB)  // 196

__global__ __launch_bounds__(SB) void k_scan1(const int* __restrict__ deg,
                                              int* __restrict__ excl,
                                              int* __restrict__ bsum) {
    __shared__ int s[SB];
    int t = threadIdx.x;
    int i = blockIdx.x * SB + t;
    int v = (i < NN) ? deg[i] : 0;
    s[t] = v;
    __syncthreads();
    for (int off = 1; off < SB; off <<= 1) {
        int x = (t >= off) ? s[t - off] : 0;
        __syncthreads();
        s[t] += x;
        __syncthreads();
    }
    if (i < NN) excl[i] = s[t] - v;
    if (t == SB - 1) bsum[blockIdx.x] = s[t];
}

__global__ __launch_bounds__(SB) void k_scan2(int* __restrict__ bsum) {
    __shared__ int s[SB];
    int t = threadIdx.x;
    int v = (t < NBLK) ? bsum[t] : 0;
    s[t] = v;
    __syncthreads();
    for (int off = 1; off < SB; off <<= 1) {
        int x = (t >= off) ? s[t - off] : 0;
        __syncthreads();
        s[t] += x;
        __syncthreads();
    }
    if (t < NBLK) bsum[t] = s[t] - v;
    if (t == NBLK - 1) bsum[NBLK] = s[t];
}

__global__ __launch_bounds__(SB) void k_scan3(int* __restrict__ row_off,
                                              int* __restrict__ cursor,
                                              const int* __restrict__ bsum) {
    int i = blockIdx.x * SB + threadIdx.x;
    if (i < NN) {
        int r = row_off[i] + bsum[blockIdx.x];
        row_off[i] = r;
        cursor[i]  = r;
    }
    if (i == 0) row_off[NN] = bsum[NBLK];
}

__global__ void k_scatter(const void* __restrict__ ei, const int* __restrict__ flag,
                          const float* __restrict__ inv_sqrt,
                          int* __restrict__ cursor, int* __restrict__ ssrc,
                          float* __restrict__ snorm) {
    int i = blockIdx.x * blockDim.x + threadIdx.x;
    if (i < NE) {
        int f = *flag;
        int s = edge_at(ei, f, 0, i);
        int d = edge_at(ei, f, 1, i);
        if ((unsigned)s < NN && (unsigned)d < NN) {
            int pos = atomicAdd(&cursor[d], 1);
            if ((unsigned)pos < NE) {
                ssrc[pos]  = s;
                snorm[pos] = inv_sqrt[s] * inv_sqrt[d];
            }
        }
    }
}

// ---------------- weight convert + transpose: Wt[n][k] = bf16(W[k][n]) ----------------
__global__ void k_wt(const float* __restrict__ W, u16* __restrict__ Wt, int K, int N) {
    int i = blockIdx.x * 256 + threadIdx.x;
    if (i < K * N) {
        int k = i / N, n = i - k * N;
        Wt[(size_t)n * K + k] = f2bf(W[i]);
    }
}

// ---------------- CSR aggregation ----------------
template <int W, int TIN, int TOUT, bool BIAS, bool RELU>
__global__ __launch_bounds__(64) void k_agg(const void* __restrict__ Xv, void* __restrict__ Yv,
                      const int* __restrict__ row_off, const int* __restrict__ ssrc,
                      const float* __restrict__ snorm, const float* __restrict__ inv_deg,
                      const float* __restrict__ bias) {
    constexpr int E = W / 64;
    int node = blockIdx.x;
    int lane = threadIdx.x;
    int col = lane * E;
    int beg = row_off[node], end = row_off[node + 1];
    float acc[E];
#pragma unroll
    for (int v = 0; v < E; v++) acc[v] = 0.f;

    auto accum = [&](int srow, float w) {
        if constexpr (TIN == 0) {
            const float* r = (const float*)Xv + (size_t)srow * W + col;
            if constexpr (E == 2) {
                float2 t = *(const float2*)r;
                acc[0] = fmaf(t.x, w, acc[0]);
                acc[1] = fmaf(t.y, w, acc[1]);
            } else {
                float4 t0 = *(const float4*)r;
                float4 t1 = *(const float4*)(r + 4);
                acc[0] = fmaf(t0.x, w, acc[0]); acc[1] = fmaf(t0.y, w, acc[1]);
                acc[2] = fmaf(t0.z, w, acc[2]); acc[3] = fmaf(t0.w, w, acc[3]);
                acc[4] = fmaf(t1.x, w, acc[4]); acc[5] = fmaf(t1.y, w, acc[5]);
                acc[6] = fmaf(t1.z, w, acc[6]); acc[7] = fmaf(t1.w, w, acc[7]);
            }
        } else {
            const u16* r = (const u16*)Xv + (size_t)srow * W + col;
            if constexpr (E == 2) {
                unsigned t = *(const unsigned*)r;
                acc[0] = fmaf(bf2f((u16)(t & 0xffff)), w, acc[0]);
                acc[1] = fmaf(bf2f((u16)(t >> 16)), w, acc[1]);
            } else {
                u16x8 t = *(const u16x8*)r;
#pragma unroll
                for (int j = 0; j < 8; j++) acc[j] = fmaf(bf2f(t[j]), w, acc[j]);
            }
        }
    };

    for (int e = beg; e < end; e++) {
        int s = ssrc[e];
        if ((unsigned)s >= NN) continue;
        accum(s, snorm[e]);
    }
    accum(node, inv_deg[node]);

#pragma unroll
    for (int v = 0; v < E; v++) {
        float val = acc[v];
        if (BIAS) val += bias[col + v];
        if (RELU) val = fmaxf(val, 0.f);
        if constexpr (TOUT == 0) ((float*)Yv)[(size_t)node * W + col + v] = val;
        else ((u16*)Yv)[(size_t)node * W + col + v] = f2bf(val);
    }
}

#define LDS_AS(p) ((__attribute__((address_space(3))) void*)(p))
#define GLB_AS(p) ((const __attribute__((address_space(1))) void*)(p))

// ---------------- 128x128 bf16 MFMA GEMM with coalesced LDS epilogue ----------------
// C[M][N] = A[M][K] * Bt[N][K]^T. 4 waves (2x2), 16x16x32 MFMA,
// global_load_lds width-16 staging. Epilogue: stage each wave's 64x64 bf16
// tile in LDS (pad 68 -> conflict-free b16 writes), read back row-contiguous
// 16B/lane, store 8x dwordx4 -> full 128B lines (kills the ~2x partial-sector
// HBM write/RMW amplification seen in rounds 4/5).
#define GBM 128
#define GBN 128
#define GBK 32
#define EPAD 68  // row stride 136B: write-side conflict-free, read-side <=2-4 way

template <bool BIAS, bool RELU>
__global__ __launch_bounds__(256) void mfma_gemm(
    const u16* __restrict__ A, const u16* __restrict__ Bt,
    const float* __restrict__ bias, u16* __restrict__ C,
    int M, int N, int K) {
    // staging (16KB) and epilogue (4*64*EPAD*2 = 34816B) share the same LDS
    __shared__ __align__(16) char smem[4 * 64 * EPAD * 2];
    u16* As = (u16*)smem;
    u16* Bs = (u16*)(smem + 8192);
    const int tid = threadIdx.x;
    const int lane = tid & 63;
    const int wave = tid >> 6;
    const int wr = wave >> 1, wc = wave & 1;
    const int bm = blockIdx.y * GBM;
    const int bn = blockIdx.x * GBN;

    f32x4 acc[4][4];
#pragma unroll
    for (int m = 0; m < 4; m++)
#pragma unroll
        for (int n = 0; n < 4; n++) acc[m][n] = (f32x4)0.f;

    const int o = tid * 16;
    const int row0 = o >> 6;
    const int colb = o & 63;
    const int row1 = row0 + 64;

    int ar0 = bm + row0; if (ar0 >= M) ar0 = M - 1;
    int ar1 = bm + row1; if (ar1 >= M) ar1 = M - 1;
    const int br0 = bn + row0;
    const int br1 = bn + row1;
    const size_t sK = (size_t)K * 2;

    const char* Ab = (const char*)A;
    const char* Bb = (const char*)Bt;

    const int kc = (lane >> 4) << 3;
    const int fr = lane & 15;
    const u16* ApA = &As[(wr * 64 + fr) * GBK + kc];
    const u16* BpB = &Bs[(wc * 64 + fr) * GBK + kc];

    for (int k0 = 0; k0 < K; k0 += GBK) {
        const size_t kb = (size_t)k0 * 2 + colb;
        __builtin_amdgcn_global_load_lds(GLB_AS(Ab + (size_t)ar0 * sK + kb), LDS_AS((char*)As + o), 16, 0, 0);
        __builtin_amdgcn_global_load_lds(GLB_AS(Ab + (size_t)ar1 * sK + kb), LDS_AS((char*)As + o + 4096), 16, 0, 0);
        __builtin_amdgcn_global_load_lds(GLB_AS(Bb + (size_t)br0 * sK + kb), LDS_AS((char*)Bs + o), 16, 0, 0);
        __builtin_amdgcn_global_load_lds(GLB_AS(Bb + (size_t)br1 * sK + kb), LDS_AS((char*)Bs + o + 4096), 16, 0, 0);
        __syncthreads();

        bf16x8 af[4], bfr[4];
#pragma unroll
        for (int m = 0; m < 4; m++) af[m] = *(const bf16x8*)(ApA + m * 16 * GBK);
#pragma unroll
        for (int n = 0; n < 4; n++) bfr[n] = *(const bf16x8*)(BpB + n * 16 * GBK);
#pragma unroll
        for (int m = 0; m < 4; m++)
#pragma unroll
            for (int n = 0; n < 4; n++)
                acc[m][n] = __builtin_amdgcn_mfma_f32_16x16x32_bf16(af[m], bfr[n], acc[m][n], 0, 0, 0);
        __syncthreads();  // final iter's sync also fences LDS reuse below
    }

    // ---- epilogue: per-wave 64x64 tile staged in LDS, then coalesced stores ----
    u16* Es = (u16*)smem + (size_t)wave * 64 * EPAD;
    const int cr = (lane >> 4) << 2;  // 0,4,8,12
    const int cc = lane & 15;
#pragma unroll
    for (int n = 0; n < 4; n++) {
        float bv = BIAS ? bias[bn + wc * 64 + n * 16 + cc] : 0.f;
#pragma unroll
        for (int m = 0; m < 4; m++) {
#pragma unroll
            for (int j = 0; j < 4; j++) {
                float v = acc[m][n][j] + bv;
                if (RELU) v = fmaxf(v, 0.f);
                Es[(m * 16 + cr + j) * EPAD + n * 16 + cc] = f2bf(v);
            }
        }
    }
    // wave-private region: no __syncthreads needed (compiler orders lgkmcnt)
    const int rl = lane >> 3;        // 0..7 row within octet
    const int c8 = (lane & 7) * 8;   // col start (u16)
#pragma unroll
    for (int it = 0; it < 8; it++) {
        int lr = it * 8 + rl;
        u16x8 vv = *(const u16x8*)(Es + lr * EPAD + c8);
        int grow = bm + wr * 64 + lr;
        if (grow < M)
            *(u16x8*)(C + (size_t)grow * N + bn + wc * 64 + c8) = vv;
    }
}

// ---------------- f32 tiled GEMM (small FC layer) ----------------
#define TBM 64
#define TBN 64
#define TBK 16
#define LPAD 4

template <bool BIAS, bool RELU>
__global__ __launch_bounds__(256) void gemm_kernel(
    const float* __restrict__ A, const float* __restrict__ B,
    const float* __restrict__ bias, float* __restrict__ C,
    int M, int N, int K) {
    __shared__ float Asl[TBK][TBM + LPAD];
    __shared__ float Bsl[TBK][TBN + LPAD];
    const int bm = blockIdx.y * TBM;
    const int bn = blockIdx.x * TBN;
    const int tid = threadIdx.x;
    const int tx = tid & 15;
    const int ty = tid >> 4;
    const int la_m = tid >> 2;
    const int la_k = (tid & 3) << 2;
    const int lb_k = tid >> 4;
    const int lb_n = (tid & 15) << 2;

    float acc[4][4];
#pragma unroll
    for (int i = 0; i < 4; i++)
#pragma unroll
        for (int j = 0; j < 4; j++) acc[i][j] = 0.f;

    const int am = bm + la_m;
    const bool a_ok = am < M;
    const int bng = bn + lb_n;

    for (int k0 = 0; k0 < K; k0 += TBK) {
        float4 av = make_float4(0.f, 0.f, 0.f, 0.f);
        if (a_ok) av = *(const float4*)(A + (size_t)am * K + k0 + la_k);
        float4 bv = make_float4(0.f, 0.f, 0.f, 0.f);
        {
            const float* Bp = B + (size_t)(k0 + lb_k) * N + bng;
            if (bng + 3 < N) {
                bv = *(const float4*)Bp;
            } else {
                if (bng + 0 < N) bv.x = Bp[0];
                if (bng + 1 < N) bv.y = Bp[1];
                if (bng + 2 < N) bv.z = Bp[2];
            }
        }
        Asl[la_k + 0][la_m] = av.x;
        Asl[la_k + 1][la_m] = av.y;
        Asl[la_k + 2][la_m] = av.z;
        Asl[la_k + 3][la_m] = av.w;
        *(float4*)&Bsl[lb_k][lb_n] = bv;
        __syncthreads();
#pragma unroll
        for (int k = 0; k < TBK; k++) {
            float4 a = *(const float4*)&Asl[k][ty << 2];
            float4 b = *(const float4*)&Bsl[k][tx << 2];
            float aa[4] = {a.x, a.y, a.z, a.w};
            float bb[4] = {b.x, b.y, b.z, b.w};
#pragma unroll
            for (int i = 0; i < 4; i++)
#pragma unroll
                for (int j = 0; j < 4; j++)
                    acc[i][j] = fmaf(aa[i], bb[j], acc[i][j]);
        }
        __syncthreads();
    }
#pragma unroll
    for (int i = 0; i < 4; i++) {
        int m = bm + (ty << 2) + i;
        if (m < M) {
#pragma unroll
            for (int j = 0; j < 4; j++) {
                int n = bn + (tx << 2) + j;
                if (n < N) {
                    float v = acc[i][j];
                    if (BIAS) v += bias[n];
                    if (RELU) v = fmaxf(v, 0.f);
                    C[(size_t)m * N + n] = v;
                }
            }
        }
    }
}

// ---------------- launch ----------------
extern "C" void kernel_launch(void* const* d_in, const int* in_sizes, int n_in,
                              void* d_out, int out_size, void* d_ws, size_t ws_size,
                              hipStream_t stream) {
    const float* x   = (const float*)d_in[0];
    const void*  ei  = d_in[1];
    const float* W1  = (const float*)d_in[2];
    const float* b1  = (const float*)d_in[3];
    const float* W2  = (const float*)d_in[4];
    const float* b2  = (const float*)d_in[5];
    const float* W3  = (const float*)d_in[6];
    const float* b3  = (const float*)d_in[7];
    const float* Wfc = (const float*)d_in[8];
    const float* bfc = (const float*)d_in[9];
    float* out = (float*)d_out;

    char* ws = (char*)d_ws;
    size_t off = 0;
    auto take = [&](size_t bytes) -> void* {
        off = (off + 255) & ~(size_t)255;
        void* p = ws + off;
        off += bytes;
        return p;
    };
    int*   deg     = (int*)take((size_t)NN * 4);
    int*   row_off = (int*)take((size_t)(NN + 1) * 4);
    int*   cursor  = (int*)take((size_t)NN * 4);
    float* isq     = (float*)take((size_t)NN * 4);
    float* idg     = (float*)take((size_t)NN * 4);
    int*   ssrc    = (int*)take((size_t)NE * 4);
    float* snorm   = (float*)take((size_t)NE * 4);
    int*   flag    = (int*)take(256);
    int*   bsum    = (int*)take((size_t)(NBLK + 1) * 4);
    u16*   Wt1     = (u16*)take((size_t)1024 * 128 * 2);
    u16*   Wt2     = (u16*)take((size_t)512 * 1024 * 2);
    u16*   Wt3     = (u16*)take((size_t)128 * 512 * 2);
    u16*   rA      = (u16*)take((size_t)NN * 128 * 2);   // a0, later g3
    u16*   rH      = (u16*)take((size_t)NN * 1024 * 2);  // h1, later h2
    u16*   rT      = (u16*)take((size_t)NN * 512 * 2);   // t2
    float* h3      = (float*)take((size_t)NN * 128 * 4);

    // graph setup
    k_init<<<(NN + 255) / 256, 256, 0, stream>>>(deg, flag);
    k_detect<<<(NE + 255) / 256, 256, 0, stream>>>(ei, flag);
    k_hist<<<(NE + 255) / 256, 256, 0, stream>>>(ei, flag, deg);
    k_node_setup<<<(NN + 255) / 256, 256, 0, stream>>>(deg, isq, idg);
    k_scan1<<<NBLK, SB, 0, stream>>>(deg, row_off, bsum);
    k_scan2<<<1, SB, 0, stream>>>(bsum);
    k_scan3<<<NBLK, SB, 0, stream>>>(row_off, cursor, bsum);
    k_scatter<<<(NE + 255) / 256, 256, 0, stream>>>(ei, flag, isq, cursor, ssrc, snorm);

    // weights -> bf16 transposed
    k_wt<<<(128 * 1024 + 255) / 256, 256, 0, stream>>>(W1, Wt1, 128, 1024);
    k_wt<<<(1024 * 512 + 255) / 256, 256, 0, stream>>>(W2, Wt2, 1024, 512);
    k_wt<<<(512 * 128 + 255) / 256, 256, 0, stream>>>(W3, Wt3, 512, 128);

    const int MB = (NN + GBM - 1) / GBM;  // 391

    // L1: aggregate x (f32 -> bf16), GEMM(+b1,relu) -> h1
    u16* a0 = rA;
    k_agg<128, 0, 1, false, false><<<NN, 64, 0, stream>>>(x, a0, row_off, ssrc, snorm, idg, nullptr);
    u16* h1 = rH;
    mfma_gemm<true, true><<<dim3(1024 / GBN, MB), 256, 0, stream>>>(a0, Wt1, b1, h1, NN, 1024, 128);

    // L2: GEMM -> t2, aggregate(+b2,relu) -> h2
    u16* t2 = rT;
    mfma_gemm<false, false><<<dim3(512 / GBN, MB), 256, 0, stream>>>(h1, Wt2, nullptr, t2, NN, 512, 1024);
    u16* h2 = rH;  // h1 dead
    k_agg<512, 1, 1, true, true><<<NN, 64, 0, stream>>>(t2, h2, row_off, ssrc, snorm, idg, b2);

    // L3: GEMM -> g3, aggregate(+b3,relu) -> h3 (f32)
    u16* g3 = rA;  // a0 dead
    mfma_gemm<false, false><<<dim3(128 / GBN, MB), 256, 0, stream>>>(h2, Wt3, nullptr, g3, NN, 128, 512);
    k_agg<128, 1, 0, true, true><<<NN, 64, 0, stream>>>(g3, h3, row_off, ssrc, snorm, idg, b3);

    // FC (f32)
    gemm_kernel<true, false><<<dim3(1, (NN + TBM - 1) / TBM), 256, 0, stream>>>(h3, Wfc, bfc, out, NN, 40, 128);

    (void)in_sizes; (void)n_in; (void)out_size; (void)ws_size;
}

// Round 7
// 447.272 us; speedup vs baseline: 1.1105x; 1.0230x over previous
//
#include <hip/hip_runtime.h>
#include <hip/hip_bf16.h>
#include <cstdint>
#include <cstddef>

#define NN 50000
#define NE 400000
typedef long long i64;
typedef unsigned short u16;
typedef __attribute__((ext_vector_type(8))) short bf16x8;
typedef __attribute__((ext_vector_type(8))) unsigned short u16x8;
typedef __attribute__((ext_vector_type(4))) float f32x4;

__device__ inline u16 f2bf(float f) {  // RNE
    unsigned u = __float_as_uint(f);
    u += 0x7fffu + ((u >> 16) & 1u);
    return (u16)(u >> 16);
}
__device__ inline float bf2f(u16 b) { return __uint_as_float(((unsigned)b) << 16); }

// ---------------- setup kernels ----------------
__global__ void k_init(int* __restrict__ deg, int* __restrict__ flag) {
    int i = blockIdx.x * blockDim.x + threadIdx.x;
    if (i < NN) deg[i] = 0;
    if (i == 0) *flag = 0;
}

__global__ void k_detect(const void* __restrict__ ei, int* __restrict__ flag) {
    int i = blockIdx.x * blockDim.x + threadIdx.x;
    if (i < NE) {
        i64 v = ((const i64*)ei)[i];
        if (v < 0 || v >= NN) atomicOr(flag, 1);
    }
}

__device__ inline int edge_at(const void* ei, int f32idx, int half, int i) {
    if (f32idx) return ((const int*)ei)[half * NE + i];
    return (int)((const i64*)ei)[half * NE + i];
}

__global__ void k_hist(const void* __restrict__ ei, const int* __restrict__ flag,
                       int* __restrict__ deg) {
    int i = blockIdx.x * blockDim.x + threadIdx.x;
    if (i < NE) {
        int d = edge_at(ei, *flag, 1, i);
        if ((unsigned)d < NN) atomicAdd(&deg[d], 1);
    }
}

__global__ void k_node_setup(const int* __restrict__ deg, float* __restrict__ inv_sqrt,
                             float* __restrict__ inv_deg) {
    int i = blockIdx.x * blockDim.x + threadIdx.x;
    if (i < NN) {
        float d = (float)deg[i] + 1.0f;
        inv_sqrt[i] = rsqrtf(d);
        inv_deg[i]  = 1.0f / d;
    }
}

// ---------------- 3-phase parallel scan ----------------
#define SB 256
#define NBLK ((NN + SB - 1) / SB)  // 196

__global__ __launch_bounds__(SB) void k_scan1(const int* __restrict__ deg,
                                              int* __restrict__ excl,
                                              int* __restrict__ bsum) {
    __shared__ int s[SB];
    int t = threadIdx.x;
    int i = blockIdx.x * SB + t;
    int v = (i < NN) ? deg[i] : 0;
    s[t] = v;
    __syncthreads();
    for (int off = 1; off < SB; off <<= 1) {
        int x = (t >= off) ? s[t - off] : 0;
        __syncthreads();
        s[t] += x;
        __syncthreads();
    }
    if (i < NN) excl[i] = s[t] - v;
    if (t == SB - 1) bsum[blockIdx.x] = s[t];
}

__global__ __launch_bounds__(SB) void k_scan2(int* __restrict__ bsum) {
    __shared__ int s[SB];
    int t = threadIdx.x;
    int v = (t < NBLK) ? bsum[t] : 0;
    s[t] = v;
    __syncthreads();
    for (int off = 1; off < SB; off <<= 1) {
        int x = (t >= off) ? s[t - off] : 0;
        __syncthreads();
        s[t] += x;
        __syncthreads();
    }
    if (t < NBLK) bsum[t] = s[t] - v;
    if (t == NBLK - 1) bsum[NBLK] = s[t];
}

__global__ __launch_bounds__(SB) void k_scan3(int* __restrict__ row_off,
                                              int* __restrict__ cursor,
                                              const int* __restrict__ bsum) {
    int i = blockIdx.x * SB + threadIdx.x;
    if (i < NN) {
        int r = row_off[i] + bsum[blockIdx.x];
        row_off[i] = r;
        cursor[i]  = r;
    }
    if (i == 0) row_off[NN] = bsum[NBLK];
}

__global__ void k_scatter(const void* __restrict__ ei, const int* __restrict__ flag,
                          const float* __restrict__ inv_sqrt,
                          int* __restrict__ cursor, int* __restrict__ ssrc,
                          float* __restrict__ snorm) {
    int i = blockIdx.x * blockDim.x + threadIdx.x;
    if (i < NE) {
        int f = *flag;
        int s = edge_at(ei, f, 0, i);
        int d = edge_at(ei, f, 1, i);
        if ((unsigned)s < NN && (unsigned)d < NN) {
            int pos = atomicAdd(&cursor[d], 1);
            if ((unsigned)pos < NE) {
                ssrc[pos]  = s;
                snorm[pos] = inv_sqrt[s] * inv_sqrt[d];
            }
        }
    }
}

// ---------------- weight convert + transpose: Wt[n][k] = bf16(W[k][n]) ----------------
__global__ void k_wt(const float* __restrict__ W, u16* __restrict__ Wt, int K, int N) {
    int i = blockIdx.x * 256 + threadIdx.x;
    if (i < K * N) {
        int k = i / N, n = i - k * N;
        Wt[(size_t)n * K + k] = f2bf(W[i]);
    }
}

// ---------------- CSR aggregation ----------------
template <int W, int TIN, int TOUT, bool BIAS, bool RELU>
__global__ __launch_bounds__(64) void k_agg(const void* __restrict__ Xv, void* __restrict__ Yv,
                      const int* __restrict__ row_off, const int* __restrict__ ssrc,
                      const float* __restrict__ snorm, const float* __restrict__ inv_deg,
                      const float* __restrict__ bias) {
    constexpr int E = W / 64;
    int node = blockIdx.x;
    int lane = threadIdx.x;
    int col = lane * E;
    int beg = row_off[node], end = row_off[node + 1];
    float acc[E];
#pragma unroll
    for (int v = 0; v < E; v++) acc[v] = 0.f;

    auto accum = [&](int srow, float w) {
        if constexpr (TIN == 0) {
            const float* r = (const float*)Xv + (size_t)srow * W + col;
            if constexpr (E == 2) {
                float2 t = *(const float2*)r;
                acc[0] = fmaf(t.x, w, acc[0]);
                acc[1] = fmaf(t.y, w, acc[1]);
            } else {
                float4 t0 = *(const float4*)r;
                float4 t1 = *(const float4*)(r + 4);
                acc[0] = fmaf(t0.x, w, acc[0]); acc[1] = fmaf(t0.y, w, acc[1]);
                acc[2] = fmaf(t0.z, w, acc[2]); acc[3] = fmaf(t0.w, w, acc[3]);
                acc[4] = fmaf(t1.x, w, acc[4]); acc[5] = fmaf(t1.y, w, acc[5]);
                acc[6] = fmaf(t1.z, w, acc[6]); acc[7] = fmaf(t1.w, w, acc[7]);
            }
        } else {
            const u16* r = (const u16*)Xv + (size_t)srow * W + col;
            if constexpr (E == 2) {
                unsigned t = *(const unsigned*)r;
                acc[0] = fmaf(bf2f((u16)(t & 0xffff)), w, acc[0]);
                acc[1] = fmaf(bf2f((u16)(t >> 16)), w, acc[1]);
            } else {
                u16x8 t = *(const u16x8*)r;
#pragma unroll
                for (int j = 0; j < 8; j++) acc[j] = fmaf(bf2f(t[j]), w, acc[j]);
            }
        }
    };

    for (int e = beg; e < end; e++) {
        int s = ssrc[e];
        if ((unsigned)s >= NN) continue;
        accum(s, snorm[e]);
    }
    accum(node, inv_deg[node]);

#pragma unroll
    for (int v = 0; v < E; v++) {
        float val = acc[v];
        if (BIAS) val += bias[col + v];
        if (RELU) val = fmaxf(val, 0.f);
        if constexpr (TOUT == 0) ((float*)Yv)[(size_t)node * W + col + v] = val;
        else ((u16*)Yv)[(size_t)node * W + col + v] = f2bf(val);
    }
}

#define LDS_AS(p) ((__attribute__((address_space(3))) void*)(p))
#define GLB_AS(p) ((const __attribute__((address_space(1))) void*)(p))

// ---------------- 128x128 bf16 MFMA GEMM, BK=64, T1 XCD swizzle ----------------
// C[M][N] = A[M][K] * Bt[N][K]^T. 4 waves (2x2), 16x16x32 MFMA.
// BK=64: one barrier-drain per 64 K (halves the 2-phase stall count).
// Staging: global_load_lds width-16, LINEAR LDS dest; source chunk-XOR
// ((tid&7)^(row&7)) mirrored on the ds_read side keeps b128 reads at the
// 8-bank-cycle floor. 1D grid + bijective XCD-chunk remap (m204): the
// N-column blocks sharing an A row-panel become XCD-co-resident -> A
// fetched ~1x and staging hits XCD-L2. Coalesced LDS epilogue (round 6).
#define GBM 128
#define GBN 128
#define GBK 64
#define EPAD 68

template <bool BIAS, bool RELU>
__global__ __launch_bounds__(256) void mfma_gemm(
    const u16* __restrict__ A, const u16* __restrict__ Bt,
    const float* __restrict__ bias, u16* __restrict__ C,
    int M, int N, int K, int nbx) {
    // staging 32KB (A 16KB + B 16KB) shares LDS with 34816B epilogue
    __shared__ __align__(16) char smem[4 * 64 * EPAD * 2];
    u16* As = (u16*)smem;             // 128 rows x 64 k
    u16* Bs = (u16*)(smem + 16384);
    const int tid = threadIdx.x;
    const int lane = tid & 63;
    const int wave = tid >> 6;
    const int wr = wave >> 1, wc = wave & 1;

    // T1: bijective XCD-chunked remap; logical id is x-major (col fastest)
    const int nwg = gridDim.x;
    int lg;
    { int q = nwg >> 3, r = nwg & 7, xc = blockIdx.x & 7, pos = blockIdx.x >> 3;
      lg = (xc < r ? xc * (q + 1) : r * (q + 1) + (xc - r) * q) + pos; }
    const int bm = (lg / nbx) * GBM;
    const int bn = (lg % nbx) * GBN;

    f32x4 acc[4][4];
#pragma unroll
    for (int m = 0; m < 4; m++)
#pragma unroll
        for (int n = 0; n < 4; n++) acc[m][n] = (f32x4)0.f;

    // staging: 4 x 16B per matrix per K-step per thread; dest linear
    const int rbase = tid >> 3;                        // dest row (+32*i)
    const int csw = (((tid & 7) ^ (rbase & 7)) << 4);  // swizzled src byte in 128B k-row
    const size_t sK = (size_t)K * 2;
    const char* Ab = (const char*)A;
    const char* Bb = (const char*)Bt;
    size_t ga[4], gb[4];
#pragma unroll
    for (int i = 0; i < 4; i++) {
        int r0 = rbase + 32 * i;
        int ar = bm + r0; if (ar >= M) ar = M - 1;
        int br = bn + r0; if (br >= N) br = N - 1;
        ga[i] = (size_t)ar * sK + csw;
        gb[i] = (size_t)br * sK + csw;
    }
    const int od = tid * 16;

    // fragment read offsets: row*128 + ((ks*4+g)^(fr&7))*16
    const int fr = lane & 15, g = lane >> 4;
    int aoff[2][4], boff[2][4];
#pragma unroll
    for (int ks = 0; ks < 2; ks++) {
        const int sw = (((ks << 2) + g) ^ (fr & 7)) << 4;
#pragma unroll
        for (int m = 0; m < 4; m++) {
            aoff[ks][m] = (wr * 64 + m * 16 + fr) * 128 + sw;
            boff[ks][m] = (wc * 64 + m * 16 + fr) * 128 + sw;
        }
    }

    for (int k0 = 0; k0 < K; k0 += GBK) {
        const size_t kb = (size_t)k0 * 2;
#pragma unroll
        for (int i = 0; i < 4; i++) {
            __builtin_amdgcn_global_load_lds(GLB_AS(Ab + ga[i] + kb), LDS_AS((char*)As + od + i * 4096), 16, 0, 0);
            __builtin_amdgcn_global_load_lds(GLB_AS(Bb + gb[i] + kb), LDS_AS((char*)Bs + od + i * 4096), 16, 0, 0);
        }
        __syncthreads();
#pragma unroll
        for (int ks = 0; ks < 2; ks++) {
            bf16x8 af[4], bfr[4];
#pragma unroll
            for (int n = 0; n < 4; n++) bfr[n] = *(const bf16x8*)((char*)Bs + boff[ks][n]);
#pragma unroll
            for (int m = 0; m < 4; m++) af[m] = *(const bf16x8*)((char*)As + aoff[ks][m]);
#pragma unroll
            for (int m = 0; m < 4; m++)
#pragma unroll
                for (int n = 0; n < 4; n++)
                    acc[m][n] = __builtin_amdgcn_mfma_f32_16x16x32_bf16(af[m], bfr[n], acc[m][n], 0, 0, 0);
        }
        __syncthreads();  // final iter's sync also fences LDS reuse below
    }

    // ---- epilogue: per-wave 64x64 tile staged in LDS, coalesced stores ----
    u16* Es = (u16*)smem + (size_t)wave * 64 * EPAD;
    const int cr = (lane >> 4) << 2;
    const int cc = lane & 15;
#pragma unroll
    for (int n = 0; n < 4; n++) {
        float bv = BIAS ? bias[bn + wc * 64 + n * 16 + cc] : 0.f;
#pragma unroll
        for (int m = 0; m < 4; m++) {
#pragma unroll
            for (int j = 0; j < 4; j++) {
                float v = acc[m][n][j] + bv;
                if (RELU) v = fmaxf(v, 0.f);
                Es[(m * 16 + cr + j) * EPAD + n * 16 + cc] = f2bf(v);
            }
        }
    }
    const int rl = lane >> 3;
    const int c8 = (lane & 7) * 8;
#pragma unroll
    for (int it = 0; it < 8; it++) {
        int lr = it * 8 + rl;
        u16x8 vv = *(const u16x8*)(Es + lr * EPAD + c8);
        int grow = bm + wr * 64 + lr;
        if (grow < M)
            *(u16x8*)(C + (size_t)grow * N + bn + wc * 64 + c8) = vv;
    }
}

// ---------------- f32 tiled GEMM (small FC layer) ----------------
#define TBM 64
#define TBN 64
#define TBK 16
#define LPAD 4

template <bool BIAS, bool RELU>
__global__ __launch_bounds__(256) void gemm_kernel(
    const float* __restrict__ A, const float* __restrict__ B,
    const float* __restrict__ bias, float* __restrict__ C,
    int M, int N, int K) {
    __shared__ float Asl[TBK][TBM + LPAD];
    __shared__ float Bsl[TBK][TBN + LPAD];
    const int bm = blockIdx.y * TBM;
    const int bn = blockIdx.x * TBN;
    const int tid = threadIdx.x;
    const int tx = tid & 15;
    const int ty = tid >> 4;
    const int la_m = tid >> 2;
    const int la_k = (tid & 3) << 2;
    const int lb_k = tid >> 4;
    const int lb_n = (tid & 15) << 2;

    float acc[4][4];
#pragma unroll
    for (int i = 0; i < 4; i++)
#pragma unroll
        for (int j = 0; j < 4; j++) acc[i][j] = 0.f;

    const int am = bm + la_m;
    const bool a_ok = am < M;
    const int bng = bn + lb_n;

    for (int k0 = 0; k0 < K; k0 += TBK) {
        float4 av = make_float4(0.f, 0.f, 0.f, 0.f);
        if (a_ok) av = *(const float4*)(A + (size_t)am * K + k0 + la_k);
        float4 bv = make_float4(0.f, 0.f, 0.f, 0.f);
        {
            const float* Bp = B + (size_t)(k0 + lb_k) * N + bng;
            if (bng + 3 < N) {
                bv = *(const float4*)Bp;
            } else {
                if (bng + 0 < N) bv.x = Bp[0];
                if (bng + 1 < N) bv.y = Bp[1];
                if (bng + 2 < N) bv.z = Bp[2];
            }
        }
        Asl[la_k + 0][la_m] = av.x;
        Asl[la_k + 1][la_m] = av.y;
        Asl[la_k + 2][la_m] = av.z;
        Asl[la_k + 3][la_m] = av.w;
        *(float4*)&Bsl[lb_k][lb_n] = bv;
        __syncthreads();
#pragma unroll
        for (int k = 0; k < TBK; k++) {
            float4 a = *(const float4*)&Asl[k][ty << 2];
            float4 b = *(const float4*)&Bsl[k][tx << 2];
            float aa[4] = {a.x, a.y, a.z, a.w};
            float bb[4] = {b.x, b.y, b.z, b.w};
#pragma unroll
            for (int i = 0; i < 4; i++)
#pragma unroll
                for (int j = 0; j < 4; j++)
                    acc[i][j] = fmaf(aa[i], bb[j], acc[i][j]);
        }
        __syncthreads();
    }
#pragma unroll
    for (int i = 0; i < 4; i++) {
        int m = bm + (ty << 2) + i;
        if (m < M) {
#pragma unroll
            for (int j = 0; j < 4; j++) {
                int n = bn + (tx << 2) + j;
                if (n < N) {
                    float v = acc[i][j];
                    if (BIAS) v += bias[n];
                    if (RELU) v = fmaxf(v, 0.f);
                    C[(size_t)m * N + n] = v;
                }
            }
        }
    }
}

// ---------------- launch ----------------
extern "C" void kernel_launch(void* const* d_in, const int* in_sizes, int n_in,
                              void* d_out, int out_size, void* d_ws, size_t ws_size,
                              hipStream_t stream) {
    const float* x   = (const float*)d_in[0];
    const void*  ei  = d_in[1];
    const float* W1  = (const float*)d_in[2];
    const float* b1  = (const float*)d_in[3];
    const float* W2  = (const float*)d_in[4];
    const float* b2  = (const float*)d_in[5];
    const float* W3  = (const float*)d_in[6];
    const float* b3  = (const float*)d_in[7];
    const float* Wfc = (const float*)d_in[8];
    const float* bfc = (const float*)d_in[9];
    float* out = (float*)d_out;

    char* ws = (char*)d_ws;
    size_t off = 0;
    auto take = [&](size_t bytes) -> void* {
        off = (off + 255) & ~(size_t)255;
        void* p = ws + off;
        off += bytes;
        return p;
    };
    int*   deg     = (int*)take((size_t)NN * 4);
    int*   row_off = (int*)take((size_t)(NN + 1) * 4);
    int*   cursor  = (int*)take((size_t)NN * 4);
    float* isq     = (float*)take((size_t)NN * 4);
    float* idg     = (float*)take((size_t)NN * 4);
    int*   ssrc    = (int*)take((size_t)NE * 4);
    float* snorm   = (float*)take((size_t)NE * 4);
    int*   flag    = (int*)take(256);
    int*   bsum    = (int*)take((size_t)(NBLK + 1) * 4);
    u16*   Wt1     = (u16*)take((size_t)1024 * 128 * 2);
    u16*   Wt2     = (u16*)take((size_t)512 * 1024 * 2);
    u16*   Wt3     = (u16*)take((size_t)128 * 512 * 2);
    u16*   rA      = (u16*)take((size_t)NN * 128 * 2);   // a0, later g3
    u16*   rH      = (u16*)take((size_t)NN * 1024 * 2);  // h1, later h2
    u16*   rT      = (u16*)take((size_t)NN * 512 * 2);   // t2
    float* h3      = (float*)take((size_t)NN * 128 * 4);

    // graph setup
    k_init<<<(NN + 255) / 256, 256, 0, stream>>>(deg, flag);
    k_detect<<<(NE + 255) / 256, 256, 0, stream>>>(ei, flag);
    k_hist<<<(NE + 255) / 256, 256, 0, stream>>>(ei, flag, deg);
    k_node_setup<<<(NN + 255) / 256, 256, 0, stream>>>(deg, isq, idg);
    k_scan1<<<NBLK, SB, 0, stream>>>(deg, row_off, bsum);
    k_scan2<<<1, SB, 0, stream>>>(bsum);
    k_scan3<<<NBLK, SB, 0, stream>>>(row_off, cursor, bsum);
    k_scatter<<<(NE + 255) / 256, 256, 0, stream>>>(ei, flag, isq, cursor, ssrc, snorm);

    // weights -> bf16 transposed
    k_wt<<<(128 * 1024 + 255) / 256, 256, 0, stream>>>(W1, Wt1, 128, 1024);
    k_wt<<<(1024 * 512 + 255) / 256, 256, 0, stream>>>(W2, Wt2, 1024, 512);
    k_wt<<<(512 * 128 + 255) / 256, 256, 0, stream>>>(W3, Wt3, 512, 128);

    const int MB = (NN + GBM - 1) / GBM;  // 391

    // L1: aggregate x (f32 -> bf16), GEMM(+b1,relu) -> h1
    u16* a0 = rA;
    k_agg<128, 0, 1, false, false><<<NN, 64, 0, stream>>>(x, a0, row_off, ssrc, snorm, idg, nullptr);
    u16* h1 = rH;
    mfma_gemm<true, true><<<MB * (1024 / GBN), 256, 0, stream>>>(a0, Wt1, b1, h1, NN, 1024, 128, 1024 / GBN);

    // L2: GEMM -> t2, aggregate(+b2,relu) -> h2
    u16* t2 = rT;
    mfma_gemm<false, false><<<MB * (512 / GBN), 256, 0, stream>>>(h1, Wt2, nullptr, t2, NN, 512, 1024, 512 / GBN);
    u16* h2 = rH;  // h1 dead
    k_agg<512, 1, 1, true, true><<<NN, 64, 0, stream>>>(t2, h2, row_off, ssrc, snorm, idg, b2);

    // L3: GEMM -> g3, aggregate(+b3,relu) -> h3 (f32)
    u16* g3 = rA;  // a0 dead
    mfma_gemm<false, false><<<MB, 256, 0, stream>>>(h2, Wt3, nullptr, g3, NN, 128, 512, 1);
    k_agg<128, 1, 0, true, true><<<NN, 64, 0, stream>>>(g3, h3, row_off, ssrc, snorm, idg, b3);

    // FC (f32)
    gemm_kernel<true, false><<<dim3(1, (NN + TBM - 1) / TBM), 256, 0, stream>>>(h3, Wfc, bfc, out, NN, 40, 128);

    (void)in_sizes; (void)n_in; (void)out_size; (void)ws_size;
}